// Round 7
// baseline (491.310 us; speedup 1.0000x reference)
//
#include <hip/hip_runtime.h>
#include <hip/hip_bf16.h>
#include <math.h>

#define BB 2
#define NPIX 131072            // 2*256*256

// ws float header (4-slot accumulators)
#define WS_G    0              // [slot4][B][1024]  (G[c=h*16+d][e])
#define WS_SSQ  8192           // [slot4][2][B][64] (0=q,1=k)
#define WS_M    9216           // [B][4096] folded Wp*blockdiag(attn), transposed
#define WS_HDR  17408
#define WS_M2_BYTE ((size_t)WS_HDR*4)   // m2 bf16: NPIX*64*2 = 16.78 MB

typedef __attribute__((ext_vector_type(8))) short short8;
typedef __attribute__((ext_vector_type(4))) float f32x4;

__device__ __forceinline__ unsigned short f2bf(float f) {
    unsigned u = __float_as_uint(f);
    u += 0x7FFFu + ((u >> 16) & 1u);            // RNE
    return (unsigned short)(u >> 16);
}
__device__ __forceinline__ float bf2f(unsigned short s) {
    return __uint_as_float((unsigned)s << 16);
}

// ---------------------------------------------------------------------------
// K1 (MFMA): per 64-pixel block, 4 waves x 16 px each:
//   q,k,v = x @ {Wq,Wk,Wv}^T ; m1 = mask@w1^T+b1 ; vm0 = v*m1 -> d_out ;
//   m2 = m1@w2^T+b2 -> ws bf16 ; Gram G + ssq (VALU from LDS) -> atomics.
// MFMA 16x16x32 bf16. A-frag: m=lane&15(px), k=quad*8+j. B-frag (weights)
// pre-swizzled in LDS so each lane reads its 8 bf16 as one b128.
// C/D: col=lane&15(out ch), row=quad*4+reg(px).
// LDS: wswz 40KB + qk 17KB + m1 9KB + ssq 2KB = 69.6KB -> 2 blocks/CU.
// ---------------------------------------------------------------------------
__global__ __launch_bounds__(256, 2) void k_fused(
    const float* __restrict__ x, const float* __restrict__ mask,
    const float* __restrict__ Wq, const float* __restrict__ Wk,
    const float* __restrict__ Wv,
    const float* __restrict__ w1, const float* __restrict__ b1,
    const float* __restrict__ w2, const float* __restrict__ b2,
    float* __restrict__ ws, float* __restrict__ out,
    __hip_bfloat16* __restrict__ m2out)
{
    __shared__ unsigned short wswz[20480];              // 40 KB: 40 frags x 512
    __shared__ alignas(16) unsigned short qkl[2*64*68]; // q then k, [px][68]
    __shared__ alignas(16) unsigned short m1l[64*72];   // [px][72] for A-reads
    __shared__ float s_ssq[4][2][64];
    const int tid = threadIdx.x, lane = tid & 63, w = tid >> 6;
    const int quad = lane >> 4, col = lane & 15;
    const int blk = blockIdx.x, b = blk >> 10, slot = blk & 3;
    const int pbase = blk*64 + w*16;                    // wave's global px base

    // A-frags for x and mask straight from global (fp32 -> bf16)
    short8 xA[2], mA[2];
    {
        const float* xs = x    + ((size_t)pbase + col)*64 + quad*8;
        const float* ms = mask + ((size_t)pbase + col)*64 + quad*8;
#pragma unroll
        for (int kh = 0; kh < 2; ++kh) {
            float4 a0 = *(const float4*)(xs + kh*32);
            float4 a1 = *(const float4*)(xs + kh*32 + 4);
            float4 b0 = *(const float4*)(ms + kh*32);
            float4 b1v4 = *(const float4*)(ms + kh*32 + 4);
#pragma unroll
            for (int j = 0; j < 4; ++j) {
                xA[kh][j]   = (short)f2bf((&a0.x)[j]);
                xA[kh][4+j] = (short)f2bf((&a1.x)[j]);
                mA[kh][j]   = (short)f2bf((&b0.x)[j]);
                mA[kh][4+j] = (short)f2bf((&b1v4.x)[j]);
            }
        }
    }

    // stage all 5 weight matrices bf16, pre-swizzled in B-frag order:
    // frag f = matot*2+kh; element (f, lane l, j) = W[ot*16+(l&15)][kh*32+(l>>4)*8+j]
    {
        const float* Wsrc[5] = {Wq, Wk, Wv, w1, w2};
        for (int i = tid; i < 20480; i += 256) {
            const int f = i >> 9, l = (i >> 3) & 63, j = i & 7;
            const int matot = f >> 1, kh = f & 1;
            const int mat = matot >> 2, ot = matot & 3;
            const int o = ot*16 + (l & 15);
            const int cc = kh*32 + ((l >> 4) & 3)*8 + j;
            wswz[i] = f2bf(Wsrc[mat][o*64 + cc]);
        }
    }
    __syncthreads();

    const float b1r[1] = {0.f}; (void)b1r;
    float b1v[4], b2v[4];
#pragma unroll
    for (int ot = 0; ot < 4; ++ot) {
        b1v[ot] = b1[ot*16 + col];
        b2v[ot] = b2[ot*16 + col];
    }

#define WFRAG(matot, kh) (*(const short8*)&wswz[(((matot)*2 + (kh))*64 + lane)*8])

    f32x4 vfr[4], m1fr[4];
    // q (mat 0) and k (mat 1): compute, write bf16 to qkl
#pragma unroll
    for (int mm = 0; mm < 2; ++mm) {
#pragma unroll
        for (int ot = 0; ot < 4; ++ot) {
            f32x4 acc = {0.f, 0.f, 0.f, 0.f};
            acc = __builtin_amdgcn_mfma_f32_16x16x32_bf16(xA[0], WFRAG(mm*4+ot,0), acc, 0,0,0);
            acc = __builtin_amdgcn_mfma_f32_16x16x32_bf16(xA[1], WFRAG(mm*4+ot,1), acc, 0,0,0);
            unsigned short* dst = qkl + mm*4352;
#pragma unroll
            for (int r = 0; r < 4; ++r)
                dst[(w*16 + quad*4 + r)*68 + ot*16 + col] = f2bf(acc[r]);
        }
    }
    // v (mat 2): keep frags
#pragma unroll
    for (int ot = 0; ot < 4; ++ot) {
        f32x4 acc = {0.f, 0.f, 0.f, 0.f};
        acc = __builtin_amdgcn_mfma_f32_16x16x32_bf16(xA[0], WFRAG(8+ot,0), acc, 0,0,0);
        acc = __builtin_amdgcn_mfma_f32_16x16x32_bf16(xA[1], WFRAG(8+ot,1), acc, 0,0,0);
        vfr[ot] = acc;
    }
    // m1 (mat 3) from mask: + bias, keep frags, write bf16 to m1l
#pragma unroll
    for (int ot = 0; ot < 4; ++ot) {
        f32x4 acc = {0.f, 0.f, 0.f, 0.f};
        acc = __builtin_amdgcn_mfma_f32_16x16x32_bf16(mA[0], WFRAG(12+ot,0), acc, 0,0,0);
        acc = __builtin_amdgcn_mfma_f32_16x16x32_bf16(mA[1], WFRAG(12+ot,1), acc, 0,0,0);
#pragma unroll
        for (int r = 0; r < 4; ++r) acc[r] += b1v[ot];
        m1fr[ot] = acc;
#pragma unroll
        for (int r = 0; r < 4; ++r)
            m1l[(w*16 + quad*4 + r)*72 + ot*16 + col] = f2bf(acc[r]);
    }
    // vm0 = v * m1 -> d_out
#pragma unroll
    for (int ot = 0; ot < 4; ++ot)
#pragma unroll
        for (int r = 0; r < 4; ++r)
            out[((size_t)pbase + quad*4 + r)*64 + ot*16 + col] =
                vfr[ot][r] * m1fr[ot][r];

    __builtin_amdgcn_wave_barrier();

    // m2 = m1 @ w2^T + b2 (A-frags from m1l), store bf16 to global
    {
        short8 a2[2];
#pragma unroll
        for (int kh = 0; kh < 2; ++kh)
            a2[kh] = *(const short8*)&m1l[(w*16 + col)*72 + kh*32 + quad*8];
#pragma unroll
        for (int ot = 0; ot < 4; ++ot) {
            f32x4 acc = {0.f, 0.f, 0.f, 0.f};
            acc = __builtin_amdgcn_mfma_f32_16x16x32_bf16(a2[0], WFRAG(16+ot,0), acc, 0,0,0);
            acc = __builtin_amdgcn_mfma_f32_16x16x32_bf16(a2[1], WFRAG(16+ot,1), acc, 0,0,0);
#pragma unroll
            for (int r = 0; r < 4; ++r)
                m2out[((size_t)pbase + quad*4 + r)*64 + ot*16 + col] =
                    __float2bfloat16(acc[r] + b2v[ot]);
        }
    }

    __builtin_amdgcn_wave_barrier();

    // Gram + ssq, VALU, lane = channel c (round-6 proven semantics):
    // G[c=h*16+d][e] += k[px][c] * q[px][(c&48)+e], over wave's 16 px
    float accG[16];
#pragma unroll
    for (int e = 0; e < 16; ++e) accG[e] = 0.f;
    float ssq_q = 0.f, ssq_k = 0.f;
    const int hbase = lane & 48;
#pragma unroll
    for (int p = 0; p < 16; ++p) {
        const int row = (w*16 + p)*68;
        const float kv = bf2f(qkl[4352 + row + lane]);
        const float qo = bf2f(qkl[row + lane]);
        ssq_k = fmaf(kv, kv, ssq_k);
        ssq_q = fmaf(qo, qo, ssq_q);
#pragma unroll
        for (int e4 = 0; e4 < 4; ++e4) {
            ushort4 qq = *(const ushort4*)&qkl[row + hbase + e4*4];
            accG[e4*4+0] = fmaf(kv, bf2f(qq.x), accG[e4*4+0]);
            accG[e4*4+1] = fmaf(kv, bf2f(qq.y), accG[e4*4+1]);
            accG[e4*4+2] = fmaf(kv, bf2f(qq.z), accG[e4*4+2]);
            accG[e4*4+3] = fmaf(kv, bf2f(qq.w), accG[e4*4+3]);
        }
    }

    __syncthreads();        // qkl now dead for all waves -> reuse as scratch

    float* gr = (float*)qkl;    // 2048 floats
    if (w < 2) {
#pragma unroll
        for (int e = 0; e < 16; ++e) gr[w*1024 + e*64 + lane] = accG[e];
    }
    s_ssq[w][0][lane] = ssq_q;
    s_ssq[w][1][lane] = ssq_k;
    __syncthreads();
    if (w >= 2) {
#pragma unroll
        for (int e = 0; e < 16; ++e) gr[(w-2)*1024 + e*64 + lane] += accG[e];
    }
    __syncthreads();
    float* Gg = ws + WS_G + (size_t)slot*2048 + (size_t)b*1024;
    for (int idx = tid; idx < 1024; idx += 256) {
        const int e = idx >> 6, c = idx & 63;
        atomicAdd(&Gg[c*16 + e], gr[idx] + gr[1024 + idx]);
    }
    if (tid < 128) {
        const int which = tid >> 6, cidx = tid & 63;
        float s = s_ssq[0][which][cidx] + s_ssq[1][which][cidx]
                + s_ssq[2][which][cidx] + s_ssq[3][which][cidx];
        atomicAdd(ws + WS_SSQ + (size_t)slot*256 + which*128 + b*64 + cidx, s);
    }
#undef WFRAG
}

// ---------------------------------------------------------------------------
// K2: softmax over normalized Gram (sum 4 slots), folded with Wp:
//   Mt[b][c=h*16+e][o] = sum_d Wp[o][h*16+d] * attn[b][h][d][e].  2 blocks.
// ---------------------------------------------------------------------------
__global__ __launch_bounds__(256) void k_attn(const float* __restrict__ rescale,
    const float* __restrict__ Wp, float* __restrict__ ws)
{
    __shared__ float sAtt[1024];        // [h][d][e]
    const int b = blockIdx.x, t = threadIdx.x;
    const int d = t >> 4, e = t & 15;
#pragma unroll
    for (int h = 0; h < 4; ++h) {
        float g = 0.f, nk2 = 0.f, nq2 = 0.f;
#pragma unroll
        for (int s = 0; s < 4; ++s) {
            g   += ws[WS_G + s*2048 + b*1024 + (h*16+d)*16 + e];
            nk2 += ws[WS_SSQ + s*256 + 128 + b*64 + h*16 + d];
            nq2 += ws[WS_SSQ + s*256 +   0 + b*64 + h*16 + e];
        }
        float nk = fmaxf(sqrtf(nk2), 1e-12f);
        float nq = fmaxf(sqrtf(nq2), 1e-12f);
        float val = g / (nk*nq) * rescale[h];
        float m = val;
        for (int off = 1; off < 16; off <<= 1) m = fmaxf(m, __shfl_xor(m, off, 16));
        float ev = expf(val - m);
        float s2 = ev;
        for (int off = 1; off < 16; off <<= 1) s2 += __shfl_xor(s2, off, 16);
        sAtt[h*256 + d*16 + e] = ev / s2;
    }
    __syncthreads();
    float* Mtb = ws + WS_M + (size_t)b*4096;
    for (int idx = t; idx < 4096; idx += 256) {
        const int c = idx >> 6, o = idx & 63, h = c >> 4, ee = c & 15;
        float acc = 0.f;
#pragma unroll
        for (int d2 = 0; d2 < 16; ++d2)
            acc = fmaf(Wp[o*64 + h*16 + d2], sAtt[h*256 + d2*16 + ee], acc);
        Mtb[c*64 + o] = acc;
    }
}

// ---------------------------------------------------------------------------
// K3: per 8x8 tile: dwconv5x5(m2 bf16 halo)+dwb -> sigmoid ->
//   vm = vm0(d_out)*(1+sig) -> out = Mt . vm + bp.
// ---------------------------------------------------------------------------
__global__ __launch_bounds__(256, 4) void k_final(
    const __hip_bfloat16* __restrict__ m2g, const float* __restrict__ wsM,
    const float* __restrict__ bp, const float* __restrict__ dw,
    const float* __restrict__ dwb, float* __restrict__ out)
{
    __shared__ unsigned short m2s[144*64];  // 18.4 KB bf16 halo (0 outside)
    __shared__ unsigned short Mtl[4096];    // 8 KB bf16 blocked-f4 [c4][o][u]
    __shared__ float s_vm[4][4][64];        // per-wave
    const int tid = threadIdx.x, lane = tid & 63, w = tid >> 6;
    const int bid = blockIdx.x;
    const int b = bid >> 10, tile = bid & 1023;
    const int y0 = (tile >> 5) * 8, x0 = (tile & 31) * 8;
    const int c = lane;

    const float* Msrc = wsM + (size_t)b*4096;
    for (int i = tid; i < 4096; i += 256) {
        const int o = (i >> 2) & 63, gc = (i >> 8) * 4 + (i & 3);
        Mtl[i] = f2bf(Msrc[gc*64 + o]);
    }
    for (int i2 = tid; i2 < 2304; i2 += 256) {
        const int pos = i2 >> 4, c4 = (i2 & 15) * 4;
        const int yy = pos / 12, xx = pos - yy*12;
        const int gy = y0 + yy - 2, gx = x0 + xx - 2;
        ushort4 us = make_ushort4(0, 0, 0, 0);
        if (gy >= 0 && gy < 256 && gx >= 0 && gx < 256)
            us = *(const ushort4*)&m2g[(((size_t)b*256 + gy)*256 + gx)*64 + c4];
        *(ushort4*)&m2s[pos*64 + c4] = us;
    }
    __syncthreads();

    const float dwbr = dwb[c], bpr = bp[c];
    float dwr[25];
#pragma unroll
    for (int k = 0; k < 25; ++k) dwr[k] = dw[c*25+k];

    for (int g = 0; g < 4; ++g) {
        const int p0 = w*16 + g*4;          // 4 consecutive px in one row
        const int py = p0 >> 3, px0 = p0 & 7;
        float acc[4] = {dwbr, dwbr, dwbr, dwbr};
#pragma unroll
        for (int ky = 0; ky < 5; ++ky) {
            const int rbase = ((py+ky)*12 + px0)*64 + c;
#pragma unroll
            for (int kx8 = 0; kx8 < 8; ++kx8) {
                const float tv = bf2f(m2s[rbase + kx8*64]);
#pragma unroll
                for (int j = 0; j < 4; ++j) {
                    const int kk = kx8 - j;
                    if (kk >= 0 && kk < 5)
                        acc[j] = fmaf(tv, dwr[ky*5 + kk], acc[j]);
                }
            }
        }
        size_t P[4];
#pragma unroll
        for (int j = 0; j < 4; ++j) {
            P[j] = (size_t)b*65536 + (size_t)(y0+py)*256 + (x0+px0+j);
            const float s = 1.f / (1.f + expf(-acc[j]));
            s_vm[w][j][c] = out[P[j]*64 + c] * (1.f + s);   // vm0 * (1+sig)
        }
        __builtin_amdgcn_wave_barrier();
        float oc[4] = {bpr, bpr, bpr, bpr};
        for (int c4 = 0; c4 < 16; ++c4) {
            float4 v4[4];
#pragma unroll
            for (int j = 0; j < 4; ++j)
                v4[j] = *(const float4*)&s_vm[w][j][c4*4];  // broadcast
            const ushort4 m4 = *(const ushort4*)&Mtl[c4*256 + lane*4];
            const float mf[4] = {bf2f(m4.x), bf2f(m4.y), bf2f(m4.z), bf2f(m4.w)};
#pragma unroll
            for (int u = 0; u < 4; ++u)
#pragma unroll
                for (int j = 0; j < 4; ++j)
                    oc[j] = fmaf((&v4[j].x)[u], mf[u], oc[j]);
        }
#pragma unroll
        for (int j = 0; j < 4; ++j)
            out[P[j]*64 + c] = oc[j];
        __builtin_amdgcn_wave_barrier();
    }
}

// ---------------------------------------------------------------------------
// K4 (last): PE branch dwconv3x3 -> gelu -> dwconv3x3, += d_out.
// xt and t1 bf16 in LDS; t1 outside image is ZERO (conv2 padding).
// ---------------------------------------------------------------------------
__global__ __launch_bounds__(256, 5) void k_pe(const float* __restrict__ x,
    const float* __restrict__ w1, const float* __restrict__ w2,
    float* __restrict__ out)
{
    __shared__ unsigned short xt[12*12*64];     // 18.4 KB bf16
    __shared__ unsigned short t1[10*10*64];     // 12.8 KB bf16
    const int tid = threadIdx.x;
    const int bid = blockIdx.x;
    const int b = bid >> 10, tile = bid & 1023;
    const int y0 = (tile >> 5) * 8, x0 = (tile & 31) * 8;
    const int c = tid & 63;
    float w1r[9], w2r[9];
#pragma unroll
    for (int k = 0; k < 9; ++k) { w1r[k] = w1[c*9+k]; w2r[k] = w2[c*9+k]; }

    for (int i = tid; i < 12*12*64; i += 256) {
        int yy = i / 768, xx = (i % 768) >> 6;
        int gy = y0 + yy - 2, gx = x0 + xx - 2;
        float v = 0.f;
        if (gy >= 0 && gy < 256 && gx >= 0 && gx < 256)
            v = x[(((size_t)b*256 + gy)*256 + gx)*64 + c];
        xt[i] = f2bf(v);
    }
    __syncthreads();
    for (int i = tid; i < 10*10*64; i += 256) {
        int yy = i / 640, xx = (i % 640) >> 6;
        int gy = y0 + yy - 1, gx = x0 + xx - 1;
        float val = 0.f;
        if (gy >= 0 && gy < 256 && gx >= 0 && gx < 256) {
            float acc = 0.f;
#pragma unroll
            for (int ky = 0; ky < 3; ++ky)
#pragma unroll
                for (int kx = 0; kx < 3; ++kx)
                    acc = fmaf(bf2f(xt[((yy+ky)*12 + xx+kx)*64 + c]),
                               w1r[ky*3+kx], acc);
            val = 0.5f * acc * (1.f + erff(acc * 0.70710678118654752f));
        }
        t1[i] = f2bf(val);
    }
    __syncthreads();
    for (int i = tid; i < 8*8*64; i += 256) {
        int yy = i / 512, xx = (i % 512) >> 6;
        float acc = 0.f;
#pragma unroll
        for (int ky = 0; ky < 3; ++ky)
#pragma unroll
            for (int kx = 0; kx < 3; ++kx)
                acc = fmaf(bf2f(t1[((yy+ky)*10 + xx+kx)*64 + c]),
                           w2r[ky*3+kx], acc);
        out[(((size_t)b*256 + y0+yy)*256 + x0+xx)*64 + c] += acc;
    }
}

extern "C" void kernel_launch(void* const* d_in, const int* in_sizes, int n_in,
                              void* d_out, int out_size, void* d_ws, size_t ws_size,
                              hipStream_t stream)
{
    const float* x    = (const float*)d_in[0];
    const float* mask = (const float*)d_in[1];
    const float* Wq   = (const float*)d_in[2];
    const float* Wk   = (const float*)d_in[3];
    const float* Wv   = (const float*)d_in[4];
    const float* resc = (const float*)d_in[5];
    const float* Wp   = (const float*)d_in[6];
    const float* bp   = (const float*)d_in[7];
    const float* mw1  = (const float*)d_in[8];
    const float* mb1  = (const float*)d_in[9];
    const float* mw2  = (const float*)d_in[10];
    const float* mb2  = (const float*)d_in[11];
    const float* mdw  = (const float*)d_in[12];
    const float* mdwb = (const float*)d_in[13];
    const float* pw1  = (const float*)d_in[14];
    const float* pw2  = (const float*)d_in[15];
    float* ws  = (float*)d_ws;
    __hip_bfloat16* m2 = (__hip_bfloat16*)((char*)d_ws + WS_M2_BYTE);
    float* out = (float*)d_out;

    hipMemsetAsync(ws, 0, (size_t)9216*sizeof(float), stream);   // G + ssq slots

    k_fused<<<2048, 256, 0, stream>>>(x, mask, Wq, Wk, Wv, mw1, mb1, mw2, mb2,
                                      ws, out, m2);              // vm0 -> d_out
    k_attn <<<2,    256, 0, stream>>>(resc, Wp, ws);
    k_final<<<2048, 256, 0, stream>>>(m2, ws + WS_M, bp, mdw, mdwb, out);
    k_pe   <<<2048, 256, 0, stream>>>(x, pw1, pw2, out);
}

// Round 8
// 293.236 us; speedup vs baseline: 1.6755x; 1.6755x over previous
//
#include <hip/hip_runtime.h>
#include <hip/hip_bf16.h>
#include <math.h>

#define BB 2
#define NPIX 131072            // 2*256*256

// ws float header (4-slot accumulators)
#define WS_G    0              // [slot4][B][1024]  (G[c=h*16+d][e])
#define WS_SSQ  8192           // [slot4][2][B][64] (0=q,1=k)
#define WS_M    9216           // [B][4096] folded Wp*blockdiag(attn), transposed
#define WS_WSWZ_BYTE ((size_t)17408*4)            // 20480 ushort pre-swizzled weights (40 KB)
#define WS_M2_BYTE   (WS_WSWZ_BYTE + 40960)       // m2 bf16: NPIX*64*2 = 16.78 MB

typedef __attribute__((ext_vector_type(8))) short short8;
typedef __attribute__((ext_vector_type(4))) float f32x4;

__device__ __forceinline__ unsigned short f2bf(float f) {
    unsigned u = __float_as_uint(f);
    u += 0x7FFFu + ((u >> 16) & 1u);            // RNE
    return (unsigned short)(u >> 16);
}
__device__ __forceinline__ float bf2f(unsigned short s) {
    return __uint_as_float((unsigned)s << 16);
}
__device__ __forceinline__ void lds_fence() {
    __asm__ __volatile__("s_waitcnt lgkmcnt(0)" ::: "memory");
}

// ---------------------------------------------------------------------------
// K0: pre-swizzle the 5 weight matrices into MFMA B-frag order, bf16, in ws.
// frag f = matot*2+kh; element (f, lane l, j) = W[ot*16+(l&15)][kh*32+((l>>4)&3)*8+j]
// ---------------------------------------------------------------------------
__global__ __launch_bounds__(256) void k_prep(const float* __restrict__ Wq,
    const float* __restrict__ Wk, const float* __restrict__ Wv,
    const float* __restrict__ w1, const float* __restrict__ w2,
    unsigned short* __restrict__ wg)
{
    const int i = blockIdx.x*256 + threadIdx.x;     // 80 blocks -> 20480
    const int f = i >> 9, l = (i >> 3) & 63, j = i & 7;
    const int matot = f >> 1, kh = f & 1;
    const int mat = matot >> 2, ot = matot & 3;
    const int o = ot*16 + (l & 15);
    const int cc = kh*32 + ((l >> 4) & 3)*8 + j;
    const float* Wsrc[5] = {Wq, Wk, Wv, w1, w2};
    wg[i] = f2bf(Wsrc[mat][o*64 + cc]);
}

// ---------------------------------------------------------------------------
// K1 (MFMA, fused): per 256-px block (512 blocks, exactly 2/CU):
//   q,k,v = x@{Wq,Wk,Wv}^T ; m1 = mask@w1^T+b1 ; vm0 = v*m1 -> d_out (fp32);
//   m2 = m1@w2^T+b2 -> ws bf16 ; Gram G + ssq -> 4-slot atomics.
// Weights: one contiguous 40KB bf16 load (pre-swizzled). All global stores
// coalesced via per-wave 4.25KB LDS scratch (phase-aliased qk/vm0/m1/m2).
// LDS = 40 + 17 + 2 = 59.5 KB -> 2 blocks/CU.
// ---------------------------------------------------------------------------
__global__ __launch_bounds__(256, 2) void k_fused(
    const float* __restrict__ x, const float* __restrict__ mask,
    const unsigned short* __restrict__ wg,
    const float* __restrict__ b1, const float* __restrict__ b2,
    float* __restrict__ ws, float* __restrict__ out,
    __hip_bfloat16* __restrict__ m2out)
{
    __shared__ unsigned short wswz[20480];          // 40 KB
    __shared__ unsigned short scr[4][2176];         // 4.25 KB per wave
    __shared__ float s_ssq[4][2][64];               // 2 KB
    const int tid = threadIdx.x, lane = tid & 63, w = tid >> 6;
    const int quad = lane >> 4, col = lane & 15;
    const int blk = blockIdx.x, b = blk >> 8, slot = blk & 3;

    for (int i = tid; i < 2560; i += 256)           // 40KB contiguous b128
        ((uint4*)wswz)[i] = ((const uint4*)wg)[i];
    __syncthreads();

    float b1v[4], b2v[4];
#pragma unroll
    for (int ot = 0; ot < 4; ++ot) {
        b1v[ot] = b1[ot*16 + col];
        b2v[ot] = b2[ot*16 + col];
    }

#define WFRAG(matot, kh) (*(const short8*)&wswz[(((matot)*2 + (kh))*64 + lane)*8])

    float accG[16];
#pragma unroll
    for (int e = 0; e < 16; ++e) accG[e] = 0.f;
    float ssq_q = 0.f, ssq_k = 0.f;
    const int hbase = lane & 48;
    unsigned short* S = scr[w];

    for (int t = 0; t < 4; ++t) {
        const int pbase = blk*256 + t*64 + w*16;

        // A-frags from global (fp32 -> bf16): A[m=col(px)][k=quad*8+j (+32kh)]
        short8 xA[2], mA[2];
        {
            const float* xs = x    + ((size_t)(pbase + col))*64 + quad*8;
            const float* ms = mask + ((size_t)(pbase + col))*64 + quad*8;
#pragma unroll
            for (int kh = 0; kh < 2; ++kh) {
                float4 a0 = *(const float4*)(xs + kh*32);
                float4 a1 = *(const float4*)(xs + kh*32 + 4);
                float4 b0 = *(const float4*)(ms + kh*32);
                float4 b1f = *(const float4*)(ms + kh*32 + 4);
#pragma unroll
                for (int j = 0; j < 4; ++j) {
                    xA[kh][j]   = (short)f2bf((&a0.x)[j]);
                    xA[kh][4+j] = (short)f2bf((&a1.x)[j]);
                    mA[kh][j]   = (short)f2bf((&b0.x)[j]);
                    mA[kh][4+j] = (short)f2bf((&b1f.x)[j]);
                }
            }
        }

        // Phase A: q,k -> S as ushort [mat][p][68]
#pragma unroll
        for (int mm = 0; mm < 2; ++mm) {
#pragma unroll
            for (int ot = 0; ot < 4; ++ot) {
                f32x4 a = {0.f, 0.f, 0.f, 0.f};
                a = __builtin_amdgcn_mfma_f32_16x16x32_bf16(xA[0], WFRAG(mm*4+ot,0), a, 0,0,0);
                a = __builtin_amdgcn_mfma_f32_16x16x32_bf16(xA[1], WFRAG(mm*4+ot,1), a, 0,0,0);
#pragma unroll
                for (int r = 0; r < 4; ++r)
                    S[mm*1088 + (quad*4+r)*68 + ot*16 + col] = f2bf(a[r]);
            }
        }
        __builtin_amdgcn_wave_barrier();
        // Gram + ssq (lane = channel c): G[c][e] += k[p][c]*q[p][(c&48)+e]
#pragma unroll
        for (int p = 0; p < 16; ++p) {
            const float kv = bf2f(S[1088 + p*68 + lane]);
            const float qo = bf2f(S[p*68 + lane]);
            ssq_k = fmaf(kv, kv, ssq_k);
            ssq_q = fmaf(qo, qo, ssq_q);
#pragma unroll
            for (int e4 = 0; e4 < 4; ++e4) {
                ushort4 qq = *(const ushort4*)&S[p*68 + hbase + e4*4];
                accG[e4*4+0] = fmaf(kv, bf2f(qq.x), accG[e4*4+0]);
                accG[e4*4+1] = fmaf(kv, bf2f(qq.y), accG[e4*4+1]);
                accG[e4*4+2] = fmaf(kv, bf2f(qq.z), accG[e4*4+2]);
                accG[e4*4+3] = fmaf(kv, bf2f(qq.w), accG[e4*4+3]);
            }
        }
        lds_fence();                    // Gram reads done before S reused

        // v, m1
        f32x4 vfr[4], m1fr[4];
#pragma unroll
        for (int ot = 0; ot < 4; ++ot) {
            f32x4 a = {0.f, 0.f, 0.f, 0.f};
            a = __builtin_amdgcn_mfma_f32_16x16x32_bf16(xA[0], WFRAG(8+ot,0), a, 0,0,0);
            a = __builtin_amdgcn_mfma_f32_16x16x32_bf16(xA[1], WFRAG(8+ot,1), a, 0,0,0);
            vfr[ot] = a;
        }
#pragma unroll
        for (int ot = 0; ot < 4; ++ot) {
            f32x4 a = {0.f, 0.f, 0.f, 0.f};
            a = __builtin_amdgcn_mfma_f32_16x16x32_bf16(mA[0], WFRAG(12+ot,0), a, 0,0,0);
            a = __builtin_amdgcn_mfma_f32_16x16x32_bf16(mA[1], WFRAG(12+ot,1), a, 0,0,0);
#pragma unroll
            for (int r = 0; r < 4; ++r) a[r] += b1v[ot];
            m1fr[ot] = a;
        }

        // Phase B: vm0 fp32 [16][66] in S, then coalesced 512B row stores
        float* vscr = (float*)S;
#pragma unroll
        for (int ot = 0; ot < 4; ++ot)
#pragma unroll
            for (int r = 0; r < 4; ++r)
                vscr[(quad*4+r)*66 + ot*16 + col] = vfr[ot][r] * m1fr[ot][r];
        __builtin_amdgcn_wave_barrier();
        {
            const int rb = lane >> 5, ci = (lane & 31)*2;
#pragma unroll
            for (int pp = 0; pp < 8; ++pp) {
                const int row = pp*2 + rb;
                float2 v2 = *(const float2*)&vscr[row*66 + ci];
                *(float2*)&out[((size_t)(pbase + row))*64 + ci] = v2;
            }
        }
        lds_fence();                    // vm0 reads done before S reused

        // Phase C: m1 bf16 [16][72] in S -> A-frags for m2
#pragma unroll
        for (int ot = 0; ot < 4; ++ot)
#pragma unroll
            for (int r = 0; r < 4; ++r)
                S[(quad*4+r)*72 + ot*16 + col] = f2bf(m1fr[ot][r]);
        __builtin_amdgcn_wave_barrier();
        short8 a2[2];
#pragma unroll
        for (int kh = 0; kh < 2; ++kh)
            a2[kh] = *(const short8*)&S[col*72 + kh*32 + quad*8];
        lds_fence();                    // a2 reads done before S overwritten

        // Phase D: m2 mfma, bf16 [16][72] in S, coalesced packed-uint stores
#pragma unroll
        for (int ot = 0; ot < 4; ++ot) {
            f32x4 a = {0.f, 0.f, 0.f, 0.f};
            a = __builtin_amdgcn_mfma_f32_16x16x32_bf16(a2[0], WFRAG(16+ot,0), a, 0,0,0);
            a = __builtin_amdgcn_mfma_f32_16x16x32_bf16(a2[1], WFRAG(16+ot,1), a, 0,0,0);
#pragma unroll
            for (int r = 0; r < 4; ++r)
                S[(quad*4+r)*72 + ot*16 + col] = f2bf(a[r] + b2v[ot]);
        }
        __builtin_amdgcn_wave_barrier();
        {
            unsigned short* m2u = (unsigned short*)m2out;
            const int rb = lane >> 5, ci = (lane & 31)*2;
#pragma unroll
            for (int pp = 0; pp < 8; ++pp) {
                const int row = pp*2 + rb;
                unsigned vv = *(const unsigned*)&S[row*72 + ci];
                *(unsigned*)&m2u[((size_t)(pbase + row))*64 + ci] = vv;
            }
        }
        lds_fence();                    // m2 reads done before next iter
    }

    __syncthreads();                    // all waves done with scr

    // two-phase block reduction of G (2048 floats in scr), layout [w2][e][lane]
    float* gr = (float*)&scr[0][0];
    if (w < 2) {
#pragma unroll
        for (int e = 0; e < 16; ++e) gr[w*1024 + e*64 + lane] = accG[e];
    }
    s_ssq[w][0][lane] = ssq_q;
    s_ssq[w][1][lane] = ssq_k;
    __syncthreads();
    if (w >= 2) {
#pragma unroll
        for (int e = 0; e < 16; ++e) gr[(w-2)*1024 + e*64 + lane] += accG[e];
    }
    __syncthreads();
    float* Gg = ws + WS_G + (size_t)slot*2048 + (size_t)b*1024;
    for (int idx = tid; idx < 1024; idx += 256) {
        const int e = idx >> 6, c = idx & 63;
        atomicAdd(&Gg[c*16 + e], gr[idx] + gr[1024 + idx]);
    }
    if (tid < 128) {
        const int which = tid >> 6, cidx = tid & 63;
        float s = s_ssq[0][which][cidx] + s_ssq[1][which][cidx]
                + s_ssq[2][which][cidx] + s_ssq[3][which][cidx];
        atomicAdd(ws + WS_SSQ + (size_t)slot*256 + which*128 + b*64 + cidx, s);
    }
#undef WFRAG
}

// ---------------------------------------------------------------------------
// K2: softmax over normalized Gram (sum 4 slots), folded with Wp:
//   Mt[b][c=h*16+e][o] = sum_d Wp[o][h*16+d] * attn[b][h][d][e].  2 blocks.
// ---------------------------------------------------------------------------
__global__ __launch_bounds__(256) void k_attn(const float* __restrict__ rescale,
    const float* __restrict__ Wp, float* __restrict__ ws)
{
    __shared__ float sAtt[1024];        // [h][d][e]
    const int b = blockIdx.x, t = threadIdx.x;
    const int d = t >> 4, e = t & 15;
#pragma unroll
    for (int h = 0; h < 4; ++h) {
        float g = 0.f, nk2 = 0.f, nq2 = 0.f;
#pragma unroll
        for (int s = 0; s < 4; ++s) {
            g   += ws[WS_G + s*2048 + b*1024 + (h*16+d)*16 + e];
            nk2 += ws[WS_SSQ + s*256 + 128 + b*64 + h*16 + d];
            nq2 += ws[WS_SSQ + s*256 +   0 + b*64 + h*16 + e];
        }
        float nk = fmaxf(sqrtf(nk2), 1e-12f);
        float nq = fmaxf(sqrtf(nq2), 1e-12f);
        float val = g / (nk*nq) * rescale[h];
        float m = val;
        for (int off = 1; off < 16; off <<= 1) m = fmaxf(m, __shfl_xor(m, off, 16));
        float ev = expf(val - m);
        float s2 = ev;
        for (int off = 1; off < 16; off <<= 1) s2 += __shfl_xor(s2, off, 16);
        sAtt[h*256 + d*16 + e] = ev / s2;
    }
    __syncthreads();
    float* Mtb = ws + WS_M + (size_t)b*4096;
    for (int idx = t; idx < 4096; idx += 256) {
        const int c = idx >> 6, o = idx & 63, h = c >> 4, ee = c & 15;
        float acc = 0.f;
#pragma unroll
        for (int d2 = 0; d2 < 16; ++d2)
            acc = fmaf(Wp[o*64 + h*16 + d2], sAtt[h*256 + d2*16 + ee], acc);
        Mtb[c*64 + o] = acc;
    }
}

// ---------------------------------------------------------------------------
// K3: per 8x8 tile: dwconv5x5(m2 bf16 halo)+dwb -> sigmoid ->
//   vm = vm0(d_out)*(1+sig) -> out = Mt . vm + bp.
// ---------------------------------------------------------------------------
__global__ __launch_bounds__(256, 4) void k_final(
    const __hip_bfloat16* __restrict__ m2g, const float* __restrict__ wsM,
    const float* __restrict__ bp, const float* __restrict__ dw,
    const float* __restrict__ dwb, float* __restrict__ out)
{
    __shared__ unsigned short m2s[144*64];  // 18.4 KB bf16 halo (0 outside)
    __shared__ unsigned short Mtl[4096];    // 8 KB bf16 blocked-f4 [c4][o][u]
    __shared__ float s_vm[4][4][64];        // per-wave
    const int tid = threadIdx.x, lane = tid & 63, w = tid >> 6;
    const int bid = blockIdx.x;
    const int b = bid >> 10, tile = bid & 1023;
    const int y0 = (tile >> 5) * 8, x0 = (tile & 31) * 8;
    const int c = lane;

    const float* Msrc = wsM + (size_t)b*4096;
    for (int i = tid; i < 4096; i += 256) {
        const int o = (i >> 2) & 63, gc = (i >> 8) * 4 + (i & 3);
        Mtl[i] = f2bf(Msrc[gc*64 + o]);
    }
    for (int i2 = tid; i2 < 2304; i2 += 256) {
        const int pos = i2 >> 4, c4 = (i2 & 15) * 4;
        const int yy = pos / 12, xx = pos - yy*12;
        const int gy = y0 + yy - 2, gx = x0 + xx - 2;
        ushort4 us = make_ushort4(0, 0, 0, 0);
        if (gy >= 0 && gy < 256 && gx >= 0 && gx < 256)
            us = *(const ushort4*)&m2g[(((size_t)b*256 + gy)*256 + gx)*64 + c4];
        *(ushort4*)&m2s[pos*64 + c4] = us;
    }
    __syncthreads();

    const float dwbr = dwb[c], bpr = bp[c];
    float dwr[25];
#pragma unroll
    for (int k = 0; k < 25; ++k) dwr[k] = dw[c*25+k];

    for (int g = 0; g < 4; ++g) {
        const int p0 = w*16 + g*4;          // 4 consecutive px in one row
        const int py = p0 >> 3, px0 = p0 & 7;
        float acc[4] = {dwbr, dwbr, dwbr, dwbr};
#pragma unroll
        for (int ky = 0; ky < 5; ++ky) {
            const int rbase = ((py+ky)*12 + px0)*64 + c;
#pragma unroll
            for (int kx8 = 0; kx8 < 8; ++kx8) {
                const float tv = bf2f(m2s[rbase + kx8*64]);
#pragma unroll
                for (int j = 0; j < 4; ++j) {
                    const int kk = kx8 - j;
                    if (kk >= 0 && kk < 5)
                        acc[j] = fmaf(tv, dwr[ky*5 + kk], acc[j]);
                }
            }
        }
        size_t P[4];
#pragma unroll
        for (int j = 0; j < 4; ++j) {
            P[j] = (size_t)b*65536 + (size_t)(y0+py)*256 + (x0+px0+j);
            const float s = 1.f / (1.f + expf(-acc[j]));
            s_vm[w][j][c] = out[P[j]*64 + c] * (1.f + s);   // vm0 * (1+sig)
        }
        __builtin_amdgcn_wave_barrier();
        float oc[4] = {bpr, bpr, bpr, bpr};
        for (int c4 = 0; c4 < 16; ++c4) {
            float4 v4[4];
#pragma unroll
            for (int j = 0; j < 4; ++j)
                v4[j] = *(const float4*)&s_vm[w][j][c4*4];  // broadcast
            const ushort4 m4 = *(const ushort4*)&Mtl[c4*256 + lane*4];
            const float mf[4] = {bf2f(m4.x), bf2f(m4.y), bf2f(m4.z), bf2f(m4.w)};
#pragma unroll
            for (int u = 0; u < 4; ++u)
#pragma unroll
                for (int j = 0; j < 4; ++j)
                    oc[j] = fmaf((&v4[j].x)[u], mf[u], oc[j]);
        }
#pragma unroll
        for (int j = 0; j < 4; ++j)
            out[P[j]*64 + c] = oc[j];
        __builtin_amdgcn_wave_barrier();
    }
}

// ---------------------------------------------------------------------------
// K4 (last): PE branch dwconv3x3 -> gelu -> dwconv3x3, += d_out.
// xt and t1 bf16 in LDS; t1 outside image is ZERO (conv2 padding).
// ---------------------------------------------------------------------------
__global__ __launch_bounds__(256, 5) void k_pe(const float* __restrict__ x,
    const float* __restrict__ w1, const float* __restrict__ w2,
    float* __restrict__ out)
{
    __shared__ unsigned short xt[12*12*64];     // 18.4 KB bf16
    __shared__ unsigned short t1[10*10*64];     // 12.8 KB bf16
    const int tid = threadIdx.x;
    const int bid = blockIdx.x;
    const int b = bid >> 10, tile = bid & 1023;
    const int y0 = (tile >> 5) * 8, x0 = (tile & 31) * 8;
    const int c = tid & 63;
    float w1r[9], w2r[9];
#pragma unroll
    for (int k = 0; k < 9; ++k) { w1r[k] = w1[c*9+k]; w2r[k] = w2[c*9+k]; }

    for (int i = tid; i < 12*12*64; i += 256) {
        int yy = i / 768, xx = (i % 768) >> 6;
        int gy = y0 + yy - 2, gx = x0 + xx - 2;
        float v = 0.f;
        if (gy >= 0 && gy < 256 && gx >= 0 && gx < 256)
            v = x[(((size_t)b*256 + gy)*256 + gx)*64 + c];
        xt[i] = f2bf(v);
    }
    __syncthreads();
    for (int i = tid; i < 10*10*64; i += 256) {
        int yy = i / 640, xx = (i % 640) >> 6;
        int gy = y0 + yy - 1, gx = x0 + xx - 1;
        float val = 0.f;
        if (gy >= 0 && gy < 256 && gx >= 0 && gx < 256) {
            float acc = 0.f;
#pragma unroll
            for (int ky = 0; ky < 3; ++ky)
#pragma unroll
                for (int kx = 0; kx < 3; ++kx)
                    acc = fmaf(bf2f(xt[((yy+ky)*12 + xx+kx)*64 + c]),
                               w1r[ky*3+kx], acc);
            val = 0.5f * acc * (1.f + erff(acc * 0.70710678118654752f));
        }
        t1[i] = f2bf(val);
    }
    __syncthreads();
    for (int i = tid; i < 8*8*64; i += 256) {
        int yy = i / 512, xx = (i % 512) >> 6;
        float acc = 0.f;
#pragma unroll
        for (int ky = 0; ky < 3; ++ky)
#pragma unroll
            for (int kx = 0; kx < 3; ++kx)
                acc = fmaf(bf2f(t1[((yy+ky)*10 + xx+kx)*64 + c]),
                           w2r[ky*3+kx], acc);
        out[(((size_t)b*256 + y0+yy)*256 + x0+xx)*64 + c] += acc;
    }
}

extern "C" void kernel_launch(void* const* d_in, const int* in_sizes, int n_in,
                              void* d_out, int out_size, void* d_ws, size_t ws_size,
                              hipStream_t stream)
{
    const float* x    = (const float*)d_in[0];
    const float* mask = (const float*)d_in[1];
    const float* Wq   = (const float*)d_in[2];
    const float* Wk   = (const float*)d_in[3];
    const float* Wv   = (const float*)d_in[4];
    const float* resc = (const float*)d_in[5];
    const float* Wp   = (const float*)d_in[6];
    const float* bp   = (const float*)d_in[7];
    const float* mw1  = (const float*)d_in[8];
    const float* mb1  = (const float*)d_in[9];
    const float* mw2  = (const float*)d_in[10];
    const float* mb2  = (const float*)d_in[11];
    const float* mdw  = (const float*)d_in[12];
    const float* mdwb = (const float*)d_in[13];
    const float* pw1  = (const float*)d_in[14];
    const float* pw2  = (const float*)d_in[15];
    float* ws  = (float*)d_ws;
    unsigned short* wg = (unsigned short*)((char*)d_ws + WS_WSWZ_BYTE);
    __hip_bfloat16* m2 = (__hip_bfloat16*)((char*)d_ws + WS_M2_BYTE);
    float* out = (float*)d_out;

    hipMemsetAsync(ws, 0, (size_t)9216*sizeof(float), stream);   // G + ssq slots

    k_prep <<<80,   256, 0, stream>>>(Wq, Wk, Wv, mw1, mw2, wg);
    k_fused<<<512,  256, 0, stream>>>(x, mask, wg, mb1, mb2, ws, out, m2);
    k_attn <<<2,    256, 0, stream>>>(resc, Wp, ws);
    k_final<<<2048, 256, 0, stream>>>(m2, ws + WS_M, bp, mdw, mdwb, out);
    k_pe   <<<2048, 256, 0, stream>>>(x, pw1, pw2, out);
}